// Round 1
// baseline (111.767 us; speedup 1.0000x reference)
//
#include <hip/hip_runtime.h>

// Reference with TARGET_CORRELATION = 1.0:
//   z = c*mu + sqrt(1 - c^2) * noise * sqrt(var(mu))
//     = 1.0*mu + 0.0 * (...)   ->  z == mu exactly (all terms finite).
// The whole variance/scale pipeline is dead code; the op is a 256 MiB copy.
// Pure memory-bound: use the D2D copy engine via hipMemcpyAsync (graph-capture
// safe, ~85% of HBM peak).

extern "C" void kernel_launch(void* const* d_in, const int* in_sizes, int n_in,
                              void* d_out, int out_size, void* d_ws, size_t ws_size,
                              hipStream_t stream) {
    const float* mu = (const float*)d_in[0];
    float* out = (float*)d_out;
    size_t bytes = (size_t)out_size * sizeof(float);
    hipMemcpyAsync(out, mu, bytes, hipMemcpyDeviceToDevice, stream);
}

// Round 2
// 109.553 us; speedup vs baseline: 1.0202x; 1.0202x over previous
//
#include <hip/hip_runtime.h>

// z = 1.0*mu + sqrt(1-1.0^2)*... == mu exactly. Pure 256 MiB copy.
// hipMemcpyAsync D2D measured 4.8 TB/s (SDMA path); a compute-kernel float4
// copy measured 6.29 TB/s on this chip (m13). Use grid-stride float4 copy:
// 2048 blocks x 256 threads, 32 x 16B per thread.

__global__ void copy_f4(const float4* __restrict__ src,
                        float4* __restrict__ dst, size_t n4) {
    size_t i = (size_t)blockIdx.x * blockDim.x + threadIdx.x;
    size_t stride = (size_t)gridDim.x * blockDim.x;
    for (; i < n4; i += stride) {
        dst[i] = src[i];
    }
}

extern "C" void kernel_launch(void* const* d_in, const int* in_sizes, int n_in,
                              void* d_out, int out_size, void* d_ws, size_t ws_size,
                              hipStream_t stream) {
    const float4* mu = (const float4*)d_in[0];
    float4* out = (float4*)d_out;
    size_t n4 = (size_t)out_size / 4;   // out_size = 16384*4096, divisible by 4
    int block = 256;
    int grid = 2048;                    // 256 CUs x 8 blocks; grid-stride covers rest
    copy_f4<<<grid, block, 0, stream>>>(mu, out, n4);
}